// Round 6
// baseline (402.323 us; speedup 1.0000x reference)
//
#include <hip/hip_runtime.h>

#define N_NODES 50000
#define E_EDGES 800000
#define IN_DIM  512
#define HID     256
#define OUTD    64

#define M_PAD   50048              // 391 * 128
#define SCAN_NB  49                // ceil(50000/1024)
#define PAD_N    (SCAN_NB * 1024)  // 50176

typedef unsigned int uint;
typedef unsigned short ushort;

using short8 = __attribute__((ext_vector_type(8))) short;
using f32x4  = __attribute__((ext_vector_type(4))) float;

__device__ __forceinline__ ushort f2bf(float f) {
    union { float f; uint u; } v; v.f = f;
    uint u = v.u;
    uint r = (u + 0x7FFFu + ((u >> 16) & 1u)) >> 16;  // RNE
    return (ushort)r;
}

__device__ __forceinline__ float bf2f(ushort h) {
    union { uint u; float f; } v; v.u = ((uint)h) << 16;
    return v.f;
}

__device__ __forceinline__ uint pk2(float a, float b) {
    return (uint)f2bf(a) | ((uint)f2bf(b) << 16);
}

// ---------------------------------------------------------------- converts
// x fp32 [50000,512] -> bf16, 8 elems/thread, exact grid
__global__ __launch_bounds__(256) void cvt_x_k(const float* __restrict__ x,
                                               ushort* __restrict__ xb) {
    size_t i = (size_t)(blockIdx.x * 256 + threadIdx.x) * 8;
    float4 f0 = *(const float4*)(x + i);
    float4 f1 = *(const float4*)(x + i + 4);
    uint4 q;
    q.x = pk2(f0.x, f0.y);
    q.y = pk2(f0.z, f0.w);
    q.z = pk2(f1.x, f1.y);
    q.w = pk2(f1.z, f1.w);
    *(uint4*)(xb + i) = q;
}

// W [K,N] fp32 -> Wt [N,K] bf16
__global__ __launch_bounds__(256) void cvt_wT_k(const float* __restrict__ W,
                                                ushort* __restrict__ Wt,
                                                int Kdim, int Ndim) {
    int i = blockIdx.x * 256 + threadIdx.x;
    if (i < Kdim * Ndim) {
        int n = i / Kdim;
        int k = i - n * Kdim;
        Wt[i] = f2bf(W[(size_t)k * Ndim + n]);
    }
}

// ---------------------------------------------------------------- CSR build
__global__ void zero_i32(int* p, int n) {
    int i = blockIdx.x * 256 + threadIdx.x;
    if (i < n) p[i] = 0;
}

__global__ void hist_k(const int* __restrict__ rows, int* __restrict__ cnt) {
    int e = blockIdx.x * 256 + threadIdx.x;
    if (e < E_EDGES) atomicAdd(&cnt[rows[e]], 1);
}

__global__ __launch_bounds__(256) void scan_part_k(const int* __restrict__ cnt,
                                                   int* __restrict__ bsum) {
    __shared__ int wsum[4];
    int tid  = threadIdx.x;
    int lane = tid & 63;
    int wave = tid >> 6;
    int4 q = *(const int4*)(cnt + blockIdx.x * 1024 + tid * 4);
    int s = q.x + q.y + q.z + q.w;
    #pragma unroll
    for (int d = 32; d > 0; d >>= 1) s += __shfl_down(s, d, 64);
    if (lane == 0) wsum[wave] = s;
    __syncthreads();
    if (tid == 0) bsum[blockIdx.x] = wsum[0] + wsum[1] + wsum[2] + wsum[3];
}

__global__ __launch_bounds__(64) void scan_bsum_k(const int* __restrict__ bsum,
                                                  int* __restrict__ boff) {
    int tid = threadIdx.x;
    int v = (tid < SCAN_NB) ? bsum[tid] : 0;
    int incl = v;
    #pragma unroll
    for (int d = 1; d < 64; d <<= 1) {
        int t = __shfl_up(incl, d, 64);
        if (tid >= d) incl += t;
    }
    if (tid < SCAN_NB) boff[tid] = incl - v;
}

__global__ __launch_bounds__(256) void scan_final_k(const int* __restrict__ cnt,
                                                    const int* __restrict__ boff,
                                                    int* __restrict__ row_ptr,
                                                    int* __restrict__ row_cur) {
    __shared__ int wsum[4];
    __shared__ int woff[4];
    int tid  = threadIdx.x;
    int lane = tid & 63;
    int wave = tid >> 6;
    int base = blockIdx.x * 1024 + tid * 4;
    int4 q = *(const int4*)(cnt + base);
    int s = q.x + q.y + q.z + q.w;
    int incl = s;
    #pragma unroll
    for (int d = 1; d < 64; d <<= 1) {
        int t = __shfl_up(incl, d, 64);
        if (lane >= d) incl += t;
    }
    if (lane == 63) wsum[wave] = incl;
    __syncthreads();
    if (tid == 0) {
        int run = 0;
        #pragma unroll
        for (int w = 0; w < 4; w++) { woff[w] = run; run += wsum[w]; }
    }
    __syncthreads();
    int off = boff[blockIdx.x] + woff[wave] + (incl - s);
    int4 o;
    o.x = off;
    o.y = off + q.x;
    o.z = o.y + q.y;
    o.w = o.z + q.z;
    *(int4*)(row_ptr + base) = o;
    *(int4*)(row_cur + base) = o;
    if (blockIdx.x == 0 && tid == 0) row_ptr[N_NODES] = E_EDGES;
}

__global__ void scatter_k(const int* __restrict__ rows, const int* __restrict__ cols,
                          const float* __restrict__ vals, int* __restrict__ row_cur,
                          int* __restrict__ col_s, float* __restrict__ val_s) {
    int e = blockIdx.x * 256 + threadIdx.x;
    if (e < E_EDGES) {
        int r = rows[e];
        int p = atomicAdd(&row_cur[r], 1);
        col_s[p] = cols[e];
        val_s[p] = vals[e];
    }
}

// ---------------------------------------------------------------- GEMM bf16
// C[M,N](bf16) = A[M,K](bf16, row-major) * Bt[N,K](bf16, row-major = B^T).
// BM=128, BK=64; block = 256 thr = 4 waves; wave (RW x CW grid) computes
// WMx WN tiles of 16x16 via mfma_f32_16x16x32_bf16. LDS rows padded to
// 144 B (stride 36 banks -> 2-way aliasing, free).
template <int BN, int RW, int CW, int WM, int WN>
__global__ __launch_bounds__(256) void gemm_bf16(const ushort* __restrict__ A,
                                                 const ushort* __restrict__ Bt,
                                                 ushort* __restrict__ C,
                                                 int M, int N, int K) {
    constexpr int BM  = 128;
    constexpr int BK  = 64;
    constexpr int LDT = 72;  // ushorts per LDS row (64 + 8 pad) = 144 B
    __shared__ ushort As[BM * LDT];
    __shared__ ushort Bs[BN * LDT];

    const int tid  = threadIdx.x;
    const int lane = tid & 63;
    const int wave = tid >> 6;
    const int quad = lane >> 4;
    const int l15  = lane & 15;

    const int col0 = blockIdx.x * BN;
    const int row0 = blockIdx.y * BM;

    const int wr = (wave % RW) * (WM * 16);
    const int wc = (wave / RW) * (WN * 16);

    f32x4 acc[WM][WN] = {};

    for (int k0 = 0; k0 < K; k0 += BK) {
        // stage A: BM*BK/8 = 1024 chunks of 16B, 4 per thread
        #pragma unroll
        for (int p = 0; p < (BM * BK / 8) / 256; p++) {
            int c = tid + p * 256;
            int row = c >> 3, sub = c & 7;
            uint4 q = *(const uint4*)(A + (size_t)(row0 + row) * K + k0 + sub * 8);
            *(uint4*)&As[row * LDT + sub * 8] = q;
        }
        // stage Bt: BN*BK/8 chunks
        #pragma unroll
        for (int p = 0; p < (BN * BK / 8) / 256; p++) {
            int c = tid + p * 256;
            int row = c >> 3, sub = c & 7;
            uint4 q = *(const uint4*)(Bt + (size_t)(col0 + row) * K + k0 + sub * 8);
            *(uint4*)&Bs[row * LDT + sub * 8] = q;
        }
        __syncthreads();
        #pragma unroll
        for (int kk = 0; kk < BK; kk += 32) {
            short8 af[WM], bf[WN];
            #pragma unroll
            for (int i = 0; i < WM; i++)
                af[i] = *(const short8*)&As[(wr + i * 16 + l15) * LDT + kk + quad * 8];
            #pragma unroll
            for (int j = 0; j < WN; j++)
                bf[j] = *(const short8*)&Bs[(wc + j * 16 + l15) * LDT + kk + quad * 8];
            #pragma unroll
            for (int i = 0; i < WM; i++)
                #pragma unroll
                for (int j = 0; j < WN; j++)
                    acc[i][j] = __builtin_amdgcn_mfma_f32_16x16x32_bf16(af[i], bf[j], acc[i][j], 0, 0, 0);
        }
        __syncthreads();
    }

    // epilogue: C/D layout col=lane&15, row=quad*4+reg
    #pragma unroll
    for (int i = 0; i < WM; i++)
        #pragma unroll
        for (int j = 0; j < WN; j++)
            #pragma unroll
            for (int rr = 0; rr < 4; rr++) {
                int grow = row0 + wr + i * 16 + quad * 4 + rr;
                int gcol = col0 + wc + j * 16 + l15;
                if (grow < M) C[(size_t)grow * N + gcol] = f2bf(acc[i][j][rr]);
            }
}

// ---------------------------------------------------------------- SpMM 1
__global__ __launch_bounds__(256) void spmm1_k(const int* __restrict__ row_ptr,
                                               const int* __restrict__ col_s,
                                               const float* __restrict__ val_s,
                                               const ushort* __restrict__ h0,
                                               const float* __restrict__ b1,
                                               ushort* __restrict__ h) {
    int wave = threadIdx.x >> 6;
    int lane = threadIdx.x & 63;
    int r = blockIdx.x * 4 + wave;
    if (r >= N_NODES) return;
    int s = row_ptr[r];
    int e = row_ptr[r + 1];
    const ushort* hp = h0 + (size_t)lane * 4;
    float a0 = 0.f, a1 = 0.f, a2 = 0.f, a3 = 0.f;
    int i = s;
    for (; i + 4 <= e; i += 4) {
        int c0 = col_s[i];
        int c1 = col_s[i + 1];
        int c2 = col_s[i + 2];
        int c3 = col_s[i + 3];
        float v0 = val_s[i];
        float v1 = val_s[i + 1];
        float v2 = val_s[i + 2];
        float v3 = val_s[i + 3];
        ushort4 q0 = *(const ushort4*)(hp + (size_t)c0 * HID);
        ushort4 q1 = *(const ushort4*)(hp + (size_t)c1 * HID);
        ushort4 q2 = *(const ushort4*)(hp + (size_t)c2 * HID);
        ushort4 q3 = *(const ushort4*)(hp + (size_t)c3 * HID);
        a0 += v0 * bf2f(q0.x); a1 += v0 * bf2f(q0.y); a2 += v0 * bf2f(q0.z); a3 += v0 * bf2f(q0.w);
        a0 += v1 * bf2f(q1.x); a1 += v1 * bf2f(q1.y); a2 += v1 * bf2f(q1.z); a3 += v1 * bf2f(q1.w);
        a0 += v2 * bf2f(q2.x); a1 += v2 * bf2f(q2.y); a2 += v2 * bf2f(q2.z); a3 += v2 * bf2f(q2.w);
        a0 += v3 * bf2f(q3.x); a1 += v3 * bf2f(q3.y); a2 += v3 * bf2f(q3.z); a3 += v3 * bf2f(q3.w);
    }
    for (; i < e; i++) {
        int c = col_s[i];
        float v = val_s[i];
        ushort4 q = *(const ushort4*)(hp + (size_t)c * HID);
        a0 += v * bf2f(q.x); a1 += v * bf2f(q.y); a2 += v * bf2f(q.z); a3 += v * bf2f(q.w);
    }
    float4 bb = *(const float4*)(b1 + lane * 4);
    a0 += bb.x; a1 += bb.y; a2 += bb.z; a3 += bb.w;
    a0 = fmaxf(a0, 0.f); a1 = fmaxf(a1, 0.f); a2 = fmaxf(a2, 0.f); a3 = fmaxf(a3, 0.f);
    ushort4 o;
    o.x = f2bf(a0); o.y = f2bf(a1); o.z = f2bf(a2); o.w = f2bf(a3);
    *(ushort4*)(h + (size_t)r * HID + lane * 4) = o;
}

// ---------------------------------------------------------------- SpMM 2
__global__ __launch_bounds__(256) void spmm2_k(const int* __restrict__ row_ptr,
                                               const int* __restrict__ col_s,
                                               const float* __restrict__ val_s,
                                               const ushort* __restrict__ h2,
                                               const float* __restrict__ b2,
                                               float* __restrict__ out) {
    int wave = threadIdx.x >> 6;
    int lane = threadIdx.x & 63;
    int r = blockIdx.x * 4 + wave;
    if (r >= N_NODES) return;
    int s = row_ptr[r];
    int e = row_ptr[r + 1];
    int slot = lane >> 4;   // 0..3
    int dg   = lane & 15;   // dim group, 4 dims
    float a0 = 0.f, a1 = 0.f, a2 = 0.f, a3 = 0.f;
    const ushort* hp = h2 + (size_t)dg * 4;
    for (int i = s + slot; i < e; i += 4) {
        int c = col_s[i];
        float v = val_s[i];
        ushort4 q = *(const ushort4*)(hp + (size_t)c * OUTD);
        a0 += v * bf2f(q.x);
        a1 += v * bf2f(q.y);
        a2 += v * bf2f(q.z);
        a3 += v * bf2f(q.w);
    }
    #pragma unroll
    for (int m = 16; m < 64; m <<= 1) {
        a0 += __shfl_xor(a0, m, 64);
        a1 += __shfl_xor(a1, m, 64);
        a2 += __shfl_xor(a2, m, 64);
        a3 += __shfl_xor(a3, m, 64);
    }
    if (slot == 0) {
        float4 bb = *(const float4*)(b2 + dg * 4);
        float4 o;
        o.x = a0 + bb.x; o.y = a1 + bb.y; o.z = a2 + bb.z; o.w = a3 + bb.w;
        *(float4*)(out + (size_t)r * OUTD + dg * 4) = o;
    }
}

// ---------------------------------------------------------------- launch
extern "C" void kernel_launch(void* const* d_in, const int* in_sizes, int n_in,
                              void* d_out, int out_size, void* d_ws, size_t ws_size,
                              hipStream_t stream) {
    const float* x    = (const float*)d_in[0];
    const int*   rows = (const int*)d_in[1];
    const int*   cols = (const int*)d_in[2];
    const float* vals = (const float*)d_in[3];
    const float* W1   = (const float*)d_in[4];
    const float* b1   = (const float*)d_in[5];
    const float* W2   = (const float*)d_in[6];
    const float* b2   = (const float*)d_in[7];
    float* out = (float*)d_out;

    char* ws = (char*)d_ws;
    size_t off = 0;
    auto alloc = [&](size_t bytes) {
        char* p = ws + off;
        off = (off + bytes + 255) & ~(size_t)255;
        return p;
    };
    ushort* xb    = (ushort*)alloc((size_t)M_PAD * IN_DIM * 2);  // padded rows
    ushort* w1t   = (ushort*)alloc((size_t)HID * IN_DIM * 2);
    ushort* w2t   = (ushort*)alloc((size_t)OUTD * HID * 2);
    ushort* h0    = (ushort*)alloc((size_t)N_NODES * HID * 2);
    ushort* h     = (ushort*)alloc((size_t)M_PAD * HID * 2);     // padded rows
    ushort* h2    = (ushort*)alloc((size_t)N_NODES * OUTD * 2);
    int*    cnt   = (int*)alloc((PAD_N) * 4);
    int*    rptr  = (int*)alloc((PAD_N + 1) * 4);
    int*    rcur  = (int*)alloc((PAD_N) * 4);
    int*    bsum  = (int*)alloc(SCAN_NB * 4);
    int*    boff  = (int*)alloc(SCAN_NB * 4);
    int*    col_s = (int*)alloc((size_t)E_EDGES * 4);
    float*  val_s = (float*)alloc((size_t)E_EDGES * 4);

    // CSR build (reused by both SpMMs)
    zero_i32<<<(PAD_N + 255) / 256, 256, 0, stream>>>(cnt, PAD_N);
    hist_k<<<(E_EDGES + 255) / 256, 256, 0, stream>>>(rows, cnt);
    scan_part_k<<<SCAN_NB, 256, 0, stream>>>(cnt, bsum);
    scan_bsum_k<<<1, 64, 0, stream>>>(bsum, boff);
    scan_final_k<<<SCAN_NB, 256, 0, stream>>>(cnt, boff, rptr, rcur);
    scatter_k<<<(E_EDGES + 255) / 256, 256, 0, stream>>>(rows, cols, vals, rcur, col_s, val_s);

    // bf16 preconversion (x, W1^T, W2^T)
    cvt_x_k<<<(N_NODES * IN_DIM / 8 + 255) / 256, 256, 0, stream>>>(x, xb);
    cvt_wT_k<<<(IN_DIM * HID + 255) / 256, 256, 0, stream>>>(W1, w1t, IN_DIM, HID);
    cvt_wT_k<<<(HID * OUTD + 255) / 256, 256, 0, stream>>>(W2, w2t, HID, OUTD);

    // layer 1: h0 = x @ W1 (bf16 MFMA), then sparse aggregate + bias + relu
    gemm_bf16<128, 2, 2, 4, 4><<<dim3(HID / 128, M_PAD / 128), 256, 0, stream>>>(
        xb, w1t, h0, N_NODES, HID, IN_DIM);
    spmm1_k<<<(N_NODES + 3) / 4, 256, 0, stream>>>(rptr, col_s, val_s, h0, b1, h);

    // layer 2
    gemm_bf16<64, 4, 1, 2, 4><<<dim3(OUTD / 64, M_PAD / 128), 256, 0, stream>>>(
        h, w2t, h2, N_NODES, OUTD, HID);
    spmm2_k<<<(N_NODES + 3) / 4, 256, 0, stream>>>(rptr, col_s, val_s, h2, b2, out);
}

// Round 7
// 374.570 us; speedup vs baseline: 1.0741x; 1.0741x over previous
//
#include <hip/hip_runtime.h>

#define N_NODES 50000
#define E_EDGES 800000
#define IN_DIM  512
#define HID     256
#define OUTD    64

#define M_PAD   50048              // 391 * 128
#define SCAN_NB  49                // ceil(50000/1024)
#define PAD_N    (SCAN_NB * 1024)  // 50176

typedef unsigned int uint;
typedef unsigned short ushort;

using short8 = __attribute__((ext_vector_type(8))) short;
using f32x4  = __attribute__((ext_vector_type(4))) float;

__device__ __forceinline__ ushort f2bf(float f) {
    union { float f; uint u; } v; v.f = f;
    uint u = v.u;
    uint r = (u + 0x7FFFu + ((u >> 16) & 1u)) >> 16;  // RNE
    return (ushort)r;
}

__device__ __forceinline__ float bf2f(ushort h) {
    union { uint u; float f; } v; v.u = ((uint)h) << 16;
    return v.f;
}

__device__ __forceinline__ uint pk2(float a, float b) {
    return (uint)f2bf(a) | ((uint)f2bf(b) << 16);
}

// ---------------------------------------------------------------- converts
// W1 [512,256] and W2 [256,64] fp32 -> transposed bf16 [N,K], one launch
__global__ __launch_bounds__(256) void cvt_w_k(const float* __restrict__ W1,
                                               const float* __restrict__ W2,
                                               ushort* __restrict__ W1t,
                                               ushort* __restrict__ W2t) {
    int i = blockIdx.x * 256 + threadIdx.x;
    const int N1 = IN_DIM * HID;  // 131072
    if (i < N1) {
        int n = i / IN_DIM;
        int k = i - n * IN_DIM;
        W1t[i] = f2bf(W1[(size_t)k * HID + n]);
    } else {
        int j = i - N1;
        if (j < HID * OUTD) {
            int n = j / HID;
            int k = j - n * HID;
            W2t[j] = f2bf(W2[(size_t)k * OUTD + n]);
        }
    }
}

// ---------------------------------------------------------------- CSR build
__global__ void zero_i32(int* p, int n) {
    int i = blockIdx.x * 256 + threadIdx.x;
    if (i < n) p[i] = 0;
}

__global__ void hist_k(const int* __restrict__ rows, int* __restrict__ cnt) {
    int e = blockIdx.x * 256 + threadIdx.x;
    if (e < E_EDGES) atomicAdd(&cnt[rows[e]], 1);
}

__global__ __launch_bounds__(256) void scan_part_k(const int* __restrict__ cnt,
                                                   int* __restrict__ bsum) {
    __shared__ int wsum[4];
    int tid  = threadIdx.x;
    int lane = tid & 63;
    int wave = tid >> 6;
    int4 q = *(const int4*)(cnt + blockIdx.x * 1024 + tid * 4);
    int s = q.x + q.y + q.z + q.w;
    #pragma unroll
    for (int d = 32; d > 0; d >>= 1) s += __shfl_down(s, d, 64);
    if (lane == 0) wsum[wave] = s;
    __syncthreads();
    if (tid == 0) bsum[blockIdx.x] = wsum[0] + wsum[1] + wsum[2] + wsum[3];
}

__global__ __launch_bounds__(64) void scan_bsum_k(const int* __restrict__ bsum,
                                                  int* __restrict__ boff) {
    int tid = threadIdx.x;
    int v = (tid < SCAN_NB) ? bsum[tid] : 0;
    int incl = v;
    #pragma unroll
    for (int d = 1; d < 64; d <<= 1) {
        int t = __shfl_up(incl, d, 64);
        if (tid >= d) incl += t;
    }
    if (tid < SCAN_NB) boff[tid] = incl - v;
}

__global__ __launch_bounds__(256) void scan_final_k(const int* __restrict__ cnt,
                                                    const int* __restrict__ boff,
                                                    int* __restrict__ row_ptr,
                                                    int* __restrict__ row_cur) {
    __shared__ int wsum[4];
    __shared__ int woff[4];
    int tid  = threadIdx.x;
    int lane = tid & 63;
    int wave = tid >> 6;
    int base = blockIdx.x * 1024 + tid * 4;
    int4 q = *(const int4*)(cnt + base);
    int s = q.x + q.y + q.z + q.w;
    int incl = s;
    #pragma unroll
    for (int d = 1; d < 64; d <<= 1) {
        int t = __shfl_up(incl, d, 64);
        if (lane >= d) incl += t;
    }
    if (lane == 63) wsum[wave] = incl;
    __syncthreads();
    if (tid == 0) {
        int run = 0;
        #pragma unroll
        for (int w = 0; w < 4; w++) { woff[w] = run; run += wsum[w]; }
    }
    __syncthreads();
    int off = boff[blockIdx.x] + woff[wave] + (incl - s);
    int4 o;
    o.x = off;
    o.y = off + q.x;
    o.z = o.y + q.y;
    o.w = o.z + q.z;
    *(int4*)(row_ptr + base) = o;
    *(int4*)(row_cur + base) = o;
    if (blockIdx.x == 0 && tid == 0) row_ptr[N_NODES] = E_EDGES;
}

__global__ void scatter_k(const int* __restrict__ rows, const int* __restrict__ cols,
                          const float* __restrict__ vals, int* __restrict__ row_cur,
                          int* __restrict__ col_s, float* __restrict__ val_s) {
    int e = blockIdx.x * 256 + threadIdx.x;
    if (e < E_EDGES) {
        int r = rows[e];
        int p = atomicAdd(&row_cur[r], 1);
        col_s[p] = cols[e];
        val_s[p] = vals[e];
    }
}

// ---------------------------------------------------------------- GEMM bf16
// C[M,N](bf16) = A[M,K] * Bt[N,K](bf16 = B^T). A is fp32 (converted during
// staging) or bf16, per AF32. BM=128, BK=64; 256 thr = 4 waves; wave grid
// RW x CW, each wave WM x WN 16x16 MFMA tiles. LDS rows 144 B (2-way bank
// aliasing = free). A-tile rows >= M clamp to M-1: garbage stays in
// accumulators of rows that are never stored.
template <bool AF32, int BN, int RW, int CW, int WM, int WN>
__global__ __launch_bounds__(256) void gemm_bf16(const float* __restrict__ Af,
                                                 const ushort* __restrict__ Ab,
                                                 const ushort* __restrict__ Bt,
                                                 ushort* __restrict__ C,
                                                 int M, int N, int K) {
    constexpr int BM  = 128;
    constexpr int BK  = 64;
    constexpr int LDT = 72;  // ushorts per LDS row (64 + 8 pad) = 144 B
    __shared__ ushort As[BM * LDT];
    __shared__ ushort Bs[BN * LDT];

    const int tid  = threadIdx.x;
    const int lane = tid & 63;
    const int wave = tid >> 6;
    const int quad = lane >> 4;
    const int l15  = lane & 15;

    const int col0 = blockIdx.x * BN;
    const int row0 = blockIdx.y * BM;

    const int wr = (wave % RW) * (WM * 16);
    const int wc = (wave / RW) * (WN * 16);

    f32x4 acc[WM][WN] = {};

    for (int k0 = 0; k0 < K; k0 += BK) {
        // stage A: BM*BK elems, chunks of 8 k-elems; 4 chunks/thread
        #pragma unroll
        for (int p = 0; p < (BM * BK / 8) / 256; p++) {
            int c = tid + p * 256;
            int row = c >> 3, sub = c & 7;
            int gr = row0 + row;
            gr = gr < M ? gr : M - 1;
            uint4 q;
            if (AF32) {
                const float* pa = Af + (size_t)gr * K + k0 + sub * 8;
                float4 f0 = *(const float4*)pa;
                float4 f1 = *(const float4*)(pa + 4);
                q.x = pk2(f0.x, f0.y);
                q.y = pk2(f0.z, f0.w);
                q.z = pk2(f1.x, f1.y);
                q.w = pk2(f1.z, f1.w);
            } else {
                q = *(const uint4*)(Ab + (size_t)gr * K + k0 + sub * 8);
            }
            *(uint4*)&As[row * LDT + sub * 8] = q;
        }
        // stage Bt (always bf16, preconverted)
        #pragma unroll
        for (int p = 0; p < (BN * BK / 8) / 256; p++) {
            int c = tid + p * 256;
            int row = c >> 3, sub = c & 7;
            uint4 q = *(const uint4*)(Bt + (size_t)(col0 + row) * K + k0 + sub * 8);
            *(uint4*)&Bs[row * LDT + sub * 8] = q;
        }
        __syncthreads();
        #pragma unroll
        for (int kk = 0; kk < BK; kk += 32) {
            short8 af[WM], bf[WN];
            #pragma unroll
            for (int i = 0; i < WM; i++)
                af[i] = *(const short8*)&As[(wr + i * 16 + l15) * LDT + kk + quad * 8];
            #pragma unroll
            for (int j = 0; j < WN; j++)
                bf[j] = *(const short8*)&Bs[(wc + j * 16 + l15) * LDT + kk + quad * 8];
            #pragma unroll
            for (int i = 0; i < WM; i++)
                #pragma unroll
                for (int j = 0; j < WN; j++)
                    acc[i][j] = __builtin_amdgcn_mfma_f32_16x16x32_bf16(af[i], bf[j], acc[i][j], 0, 0, 0);
        }
        __syncthreads();
    }

    // epilogue: C/D layout col=lane&15, row=quad*4+reg
    #pragma unroll
    for (int i = 0; i < WM; i++)
        #pragma unroll
        for (int j = 0; j < WN; j++)
            #pragma unroll
            for (int rr = 0; rr < 4; rr++) {
                int grow = row0 + wr + i * 16 + quad * 4 + rr;
                int gcol = col0 + wc + j * 16 + l15;
                if (grow < M) C[(size_t)grow * N + gcol] = f2bf(acc[i][j][rr]);
            }
}

// ---------------------------------------------------------------- SpMM 1
// wave per row; lane covers dims [lane*4, lane*4+4). Edge loop unrolled x4:
// 4 independent 512B gathers in flight to break the latency chain.
__global__ __launch_bounds__(256) void spmm1_k(const int* __restrict__ row_ptr,
                                               const int* __restrict__ col_s,
                                               const float* __restrict__ val_s,
                                               const ushort* __restrict__ h0,
                                               const float* __restrict__ b1,
                                               ushort* __restrict__ h) {
    int wave = threadIdx.x >> 6;
    int lane = threadIdx.x & 63;
    int r = blockIdx.x * 4 + wave;
    if (r >= N_NODES) return;
    int s = row_ptr[r];
    int e = row_ptr[r + 1];
    const ushort* hp = h0 + (size_t)lane * 4;
    float a0 = 0.f, a1 = 0.f, a2 = 0.f, a3 = 0.f;
    int i = s;
    for (; i + 4 <= e; i += 4) {
        int c0 = col_s[i];
        int c1 = col_s[i + 1];
        int c2 = col_s[i + 2];
        int c3 = col_s[i + 3];
        float v0 = val_s[i];
        float v1 = val_s[i + 1];
        float v2 = val_s[i + 2];
        float v3 = val_s[i + 3];
        ushort4 q0 = *(const ushort4*)(hp + (size_t)c0 * HID);
        ushort4 q1 = *(const ushort4*)(hp + (size_t)c1 * HID);
        ushort4 q2 = *(const ushort4*)(hp + (size_t)c2 * HID);
        ushort4 q3 = *(const ushort4*)(hp + (size_t)c3 * HID);
        a0 += v0 * bf2f(q0.x); a1 += v0 * bf2f(q0.y); a2 += v0 * bf2f(q0.z); a3 += v0 * bf2f(q0.w);
        a0 += v1 * bf2f(q1.x); a1 += v1 * bf2f(q1.y); a2 += v1 * bf2f(q1.z); a3 += v1 * bf2f(q1.w);
        a0 += v2 * bf2f(q2.x); a1 += v2 * bf2f(q2.y); a2 += v2 * bf2f(q2.z); a3 += v2 * bf2f(q2.w);
        a0 += v3 * bf2f(q3.x); a1 += v3 * bf2f(q3.y); a2 += v3 * bf2f(q3.z); a3 += v3 * bf2f(q3.w);
    }
    for (; i < e; i++) {
        int c = col_s[i];
        float v = val_s[i];
        ushort4 q = *(const ushort4*)(hp + (size_t)c * HID);
        a0 += v * bf2f(q.x); a1 += v * bf2f(q.y); a2 += v * bf2f(q.z); a3 += v * bf2f(q.w);
    }
    float4 bb = *(const float4*)(b1 + lane * 4);
    a0 += bb.x; a1 += bb.y; a2 += bb.z; a3 += bb.w;
    a0 = fmaxf(a0, 0.f); a1 = fmaxf(a1, 0.f); a2 = fmaxf(a2, 0.f); a3 = fmaxf(a3, 0.f);
    ushort4 o;
    o.x = f2bf(a0); o.y = f2bf(a1); o.z = f2bf(a2); o.w = f2bf(a3);
    *(ushort4*)(h + (size_t)r * HID + lane * 4) = o;
}

// ---------------------------------------------------------------- SpMM 2
__global__ __launch_bounds__(256) void spmm2_k(const int* __restrict__ row_ptr,
                                               const int* __restrict__ col_s,
                                               const float* __restrict__ val_s,
                                               const ushort* __restrict__ h2,
                                               const float* __restrict__ b2,
                                               float* __restrict__ out) {
    int wave = threadIdx.x >> 6;
    int lane = threadIdx.x & 63;
    int r = blockIdx.x * 4 + wave;
    if (r >= N_NODES) return;
    int s = row_ptr[r];
    int e = row_ptr[r + 1];
    int slot = lane >> 4;   // 0..3
    int dg   = lane & 15;   // dim group, 4 dims
    float a0 = 0.f, a1 = 0.f, a2 = 0.f, a3 = 0.f;
    const ushort* hp = h2 + (size_t)dg * 4;
    for (int i = s + slot; i < e; i += 4) {
        int c = col_s[i];
        float v = val_s[i];
        ushort4 q = *(const ushort4*)(hp + (size_t)c * OUTD);
        a0 += v * bf2f(q.x);
        a1 += v * bf2f(q.y);
        a2 += v * bf2f(q.z);
        a3 += v * bf2f(q.w);
    }
    #pragma unroll
    for (int m = 16; m < 64; m <<= 1) {
        a0 += __shfl_xor(a0, m, 64);
        a1 += __shfl_xor(a1, m, 64);
        a2 += __shfl_xor(a2, m, 64);
        a3 += __shfl_xor(a3, m, 64);
    }
    if (slot == 0) {
        float4 bb = *(const float4*)(b2 + dg * 4);
        float4 o;
        o.x = a0 + bb.x; o.y = a1 + bb.y; o.z = a2 + bb.z; o.w = a3 + bb.w;
        *(float4*)(out + (size_t)r * OUTD + dg * 4) = o;
    }
}

// ---------------------------------------------------------------- launch
extern "C" void kernel_launch(void* const* d_in, const int* in_sizes, int n_in,
                              void* d_out, int out_size, void* d_ws, size_t ws_size,
                              hipStream_t stream) {
    const float* x    = (const float*)d_in[0];
    const int*   rows = (const int*)d_in[1];
    const int*   cols = (const int*)d_in[2];
    const float* vals = (const float*)d_in[3];
    const float* W1   = (const float*)d_in[4];
    const float* b1   = (const float*)d_in[5];
    const float* W2   = (const float*)d_in[6];
    const float* b2   = (const float*)d_in[7];
    float* out = (float*)d_out;

    char* ws = (char*)d_ws;
    size_t off = 0;
    auto alloc = [&](size_t bytes) {
        char* p = ws + off;
        off = (off + bytes + 255) & ~(size_t)255;
        return p;
    };
    ushort* w1t   = (ushort*)alloc((size_t)HID * IN_DIM * 2);
    ushort* w2t   = (ushort*)alloc((size_t)OUTD * HID * 2);
    ushort* h0    = (ushort*)alloc((size_t)N_NODES * HID * 2);
    ushort* h     = (ushort*)alloc((size_t)M_PAD * HID * 2);     // padded rows
    ushort* h2    = (ushort*)alloc((size_t)N_NODES * OUTD * 2);
    int*    cnt   = (int*)alloc((PAD_N) * 4);
    int*    rptr  = (int*)alloc((PAD_N + 1) * 4);
    int*    rcur  = (int*)alloc((PAD_N) * 4);
    int*    bsum  = (int*)alloc(SCAN_NB * 4);
    int*    boff  = (int*)alloc(SCAN_NB * 4);
    int*    col_s = (int*)alloc((size_t)E_EDGES * 4);
    float*  val_s = (float*)alloc((size_t)E_EDGES * 4);

    // CSR build (reused by both SpMMs)
    zero_i32<<<(PAD_N + 255) / 256, 256, 0, stream>>>(cnt, PAD_N);
    hist_k<<<(E_EDGES + 255) / 256, 256, 0, stream>>>(rows, cnt);
    scan_part_k<<<SCAN_NB, 256, 0, stream>>>(cnt, bsum);
    scan_bsum_k<<<1, 64, 0, stream>>>(bsum, boff);
    scan_final_k<<<SCAN_NB, 256, 0, stream>>>(cnt, boff, rptr, rcur);
    scatter_k<<<(E_EDGES + 255) / 256, 256, 0, stream>>>(rows, cols, vals, rcur, col_s, val_s);

    // weight transpose+convert (one launch for both)
    cvt_w_k<<<(IN_DIM * HID + HID * OUTD + 255) / 256, 256, 0, stream>>>(W1, W2, w1t, w2t);

    // layer 1: h0 = x @ W1 (fp32 A converted in staging), aggregate+bias+relu
    gemm_bf16<true, 128, 2, 2, 4, 4><<<dim3(HID / 128, M_PAD / 128), 256, 0, stream>>>(
        x, nullptr, w1t, h0, N_NODES, HID, IN_DIM);
    spmm1_k<<<(N_NODES + 3) / 4, 256, 0, stream>>>(rptr, col_s, val_s, h0, b1, h);

    // layer 2
    gemm_bf16<false, 64, 4, 1, 2, 4><<<dim3(OUTD / 64, M_PAD / 128), 256, 0, stream>>>(
        nullptr, h, w2t, h2, N_NODES, OUTD, HID);
    spmm2_k<<<(N_NODES + 3) / 4, 256, 0, stream>>>(rptr, col_s, val_s, h2, b2, out);
}